// Round 10
// baseline (608.765 us; speedup 1.0000x reference)
//
#include <hip/hip_runtime.h>
#include <hip/hip_bf16.h>

// ---- problem constants (fixed by setup_inputs) ----
#define NN   32768
#define EE   262144
#define SS   128
#define NF_  90
#define NC_  36
#define OD_  64
#define D0_  190
#define DX_  380
#define GIN_ 256
#define GH_  512

typedef __attribute__((ext_vector_type(8))) short  s8v;   // 8 bf16 = 4 VGPRs
typedef __attribute__((ext_vector_type(4))) float  f4v;   // 4 fp32

typedef const __attribute__((address_space(1))) void* gas_ptr;
typedef __attribute__((address_space(3))) void*       las_ptr;

// ---- bf16 helpers (manual, RN) ----
__device__ __forceinline__ float bf2f(unsigned u) {
  return __uint_as_float(u << 16);
}
__device__ __forceinline__ unsigned short f2bf(float f) {
  unsigned u = __float_as_uint(f);
  u += 0x7FFFu + ((u >> 16) & 1u);
  return (unsigned short)(u >> 16);
}
__device__ __forceinline__ unsigned pack2(float a, float b) {
  return ((unsigned)f2bf(b) << 16) | (unsigned)f2bf(a);
}

// ---------------------------------------------------------------------------
// degree / CSR build (parallel 3-phase scan)
// ---------------------------------------------------------------------------
__global__ void deg_count(const int* __restrict__ dst, int* __restrict__ deg) {
  int e = blockIdx.x * 256 + threadIdx.x;
  if (e < EE) atomicAdd(&deg[dst[e]], 1);
}

__global__ __launch_bounds__(256) void blk_sum_k(const int* __restrict__ deg,
                                                 int* __restrict__ bsum) {
  __shared__ int buf[256];
  int tid = threadIdx.x;
  buf[tid] = deg[blockIdx.x * 256 + tid];
  __syncthreads();
  for (int off = 128; off > 0; off >>= 1) {
    if (tid < off) buf[tid] += buf[tid + off];
    __syncthreads();
  }
  if (tid == 0) bsum[blockIdx.x] = buf[0];
}

__global__ __launch_bounds__(128) void blk_scan_k(const int* __restrict__ bsum,
                                                  int* __restrict__ boff) {
  __shared__ int buf[128];
  int tid = threadIdx.x;
  int v = bsum[tid];
  buf[tid] = v;
  __syncthreads();
  for (int d = 1; d < 128; d <<= 1) {
    int t = (tid >= d) ? buf[tid - d] : 0;
    __syncthreads();
    if (tid >= d) buf[tid] += t;
    __syncthreads();
  }
  boff[tid] = buf[tid] - v;   // exclusive
}

__global__ __launch_bounds__(256) void offsets_k(const int* __restrict__ deg,
                                                 const int* __restrict__ boff,
                                                 int* __restrict__ offsets,
                                                 float* __restrict__ inv_deg) {
  __shared__ int buf[256];
  int tid = threadIdx.x;
  int i = blockIdx.x * 256 + tid;
  int v = deg[i];
  buf[tid] = v;
  __syncthreads();
  for (int d = 1; d < 256; d <<= 1) {
    int t = (tid >= d) ? buf[tid - d] : 0;
    __syncthreads();
    if (tid >= d) buf[tid] += t;
    __syncthreads();
  }
  offsets[i] = boff[blockIdx.x] + buf[tid] - v;
  inv_deg[i] = 1.0f / fmaxf((float)v, 1.0f);
  if (i == 0) offsets[NN] = EE;
}

__global__ void bucket_k(const int* __restrict__ src, const int* __restrict__ dst,
                         const int* __restrict__ offsets, int* __restrict__ cursor,
                         int* __restrict__ srcs) {
  int e = blockIdx.x * 256 + threadIdx.x;
  if (e < EE) {
    int d = dst[e];
    int pos = offsets[d] + atomicAdd(&cursor[d], 1);
    srcs[pos] = src[e];
  }
}

// ---------------------------------------------------------------------------
// prep_all: zero stats, init out, convert+pack all weights to bf16, build x0
// packed SAGE weights: WC[j] = [wl[j] | wr[j]]
// ---------------------------------------------------------------------------
#define P1 73728          // w1b  [384x192]
#define P2 172032         // w2b  [256x384]
#define P3 434176         // WC1  [512x512]
#define P4 958464         // WC2  [512x1024]
#define P5 1482752        // WC3  [512x1024]

__global__ __launch_bounds__(256) void prep_all(
    const float* __restrict__ nf, const float* __restrict__ ncf,
    const float* __restrict__ emb, const int* __restrict__ ops,
    const float* __restrict__ w1, const float* __restrict__ w2,
    const float* __restrict__ wl1, const float* __restrict__ wr1,
    const float* __restrict__ wl2, const float* __restrict__ wr2,
    const float* __restrict__ wl3, const float* __restrict__ wr3,
    unsigned short* __restrict__ w1b, unsigned short* __restrict__ w2b,
    unsigned short* __restrict__ wc1, unsigned short* __restrict__ wc2,
    unsigned short* __restrict__ wc3,
    unsigned short* __restrict__ x0,
    float* __restrict__ stat_all, float* __restrict__ outp,
    const float* __restrict__ bc)
{
  const int T = 4096 * 256;
  int gidx = blockIdx.x * 256 + threadIdx.x;
  for (int i = gidx; i < 2560; i += T) stat_all[i] = 0.0f;
  if (gidx < SS) outp[gidx] = bc[0];
  for (int i = gidx; i < P5; i += T) {
    if (i < P1) {
      int r = i / 192, c = i - r * 192;
      w1b[i] = f2bf((r < DX_ && c < D0_) ? w1[r * D0_ + c] : 0.0f);
    } else if (i < P2) {
      int j = i - P1;
      int r = j / 384, c = j - r * 384;
      w2b[j] = f2bf((c < DX_) ? w2[r * DX_ + c] : 0.0f);
    } else if (i < P3) {
      int j = i - P2;                 // [0, 512*512)
      int r = j >> 9, c = j & 511;
      wc1[j] = f2bf((c < 256) ? wl1[r * 256 + c] : wr1[r * 256 + (c - 256)]);
    } else if (i < P4) {
      int j = i - P3;                 // [0, 512*1024)
      int r = j >> 10, c = j & 1023;
      wc2[j] = f2bf((c < 512) ? wl2[r * 512 + c] : wr2[r * 512 + (c - 512)]);
    } else {
      int j = i - P4;
      int r = j >> 10, c = j & 1023;
      wc3[j] = f2bf((c < 512) ? wl3[r * 512 + c] : wr3[r * 512 + (c - 512)]);
    }
  }
  for (int i = gidx; i < NN * 192; i += T) {
    int n = i / 192;
    int c = i - n * 192;
    float v;
    if (c < NF_)            v = nf[n * NF_ + c];
    else if (c < NF_ + NC_) v = ncf[n * NC_ + (c - NF_)];
    else if (c < D0_)       v = emb[ops[n] * OD_ + (c - (NF_ + NC_))];
    else                    v = 0.0f;
    x0[i] = f2bf(v);
  }
}

// ---------------------------------------------------------------------------
// bf16 MFMA GEMM (NT), BK=64, 512 threads = 8 waves (2x4), 128x128 tile.
// Each wave computes 64x32 via 4x2 mfma 16x16x32 -> 32 AGPRs/wave (occupancy).
// LDS: [koff(8)][row(128)][8 bf16] per matrix = 16 KB each, 32 KB total.
// mode 1: C=leaky(acc+bias) fp32, fused scalar (GLN) stats -> st0/st1[seg]
// mode 2: C=acc+bias fp32, fused column (PairNorm) stats -> st0/st1[col]
// mode 3: no C write; outp[seg] += sum_rows dot(acc+bias, wcp)
// swz=1: 1D grid 1024, XCD-aware decode keeping same-bm tiles on one XCD.
// ---------------------------------------------------------------------------
__device__ __forceinline__ void stage64(const unsigned short* __restrict__ G, int ld,
                                        int base_row, int k0,
                                        unsigned short* __restrict__ lds, int tid) {
#pragma unroll
  for (int i = 0; i < 2; ++i) {
    int c = tid + i * 512;        // 0..1023
    int row = c & 127;
    int koff = c >> 7;            // 0..7 (k chunk of 8 bf16)
    const unsigned short* src = G + (size_t)(base_row + row) * ld + k0 + koff * 8;
    unsigned short* dst = lds + koff * 1024 + row * 8;
    __builtin_amdgcn_global_load_lds((gas_ptr)(const void*)src, (las_ptr)(void*)dst,
                                     16, 0, 0);
  }
}

__global__ __launch_bounds__(512) void mfma_gemm(
    const unsigned short* __restrict__ A, int lda,
    const unsigned short* __restrict__ B, int ldb, int K,
    const float* __restrict__ bias,
    float* __restrict__ C, int ldc, int Nreal, int mode, int swz,
    float* __restrict__ st0, float* __restrict__ st1,
    const float* __restrict__ wcp, float* __restrict__ outp)
{
  __shared__ unsigned short As[8192];
  __shared__ unsigned short Bs[8192];
  int tid = threadIdx.x;
  int lane = tid & 63;
  int w = tid >> 6;            // 0..7
  int wm = (w & 1) * 64;
  int wn = (w >> 1) * 32;      // 0,32,64,96
  int bm, bn;
  if (swz) {
    int L = blockIdx.x;
    int xcd = L & 7;
    int s = L >> 3;
    bn = (s & 3) * 128;
    bm = ((s >> 2) * 8 + xcd) * 128;
  } else {
    bm = blockIdx.y * 128;
    bn = blockIdx.x * 128;
  }
  int quad = lane >> 4;      // 0..3
  int r16 = lane & 15;

  f4v acc[4][2] = {};

  for (int k0 = 0; k0 < K; k0 += 64) {
    stage64(A, lda, bm, k0, As, tid);
    stage64(B, ldb, bn, k0, Bs, tid);
    __syncthreads();
#pragma unroll
    for (int s = 0; s < 2; ++s) {
      s8v af[4], bfr[2];
#pragma unroll
      for (int mi = 0; mi < 4; ++mi)
        af[mi] = *(const s8v*)&As[(s * 4 + quad) * 1024 + (wm + mi * 16 + r16) * 8];
#pragma unroll
      for (int ni = 0; ni < 2; ++ni)
        bfr[ni] = *(const s8v*)&Bs[(s * 4 + quad) * 1024 + (wn + ni * 16 + r16) * 8];
#pragma unroll
      for (int mi = 0; mi < 4; ++mi)
#pragma unroll
        for (int ni = 0; ni < 2; ++ni)
          acc[mi][ni] = __builtin_amdgcn_mfma_f32_16x16x32_bf16(
              af[mi], bfr[ni], acc[mi][ni], 0, 0, 0);
    }
    __syncthreads();
  }

  // epilogue scratch overlays the (now dead) staging LDS
  float* red = (float*)As;            // 512 floats
  float* cs  = (float*)Bs;            // 128 floats
  float* css = ((float*)Bs) + 128;    // 128 floats

  int seg = bm >> 8;

  if (mode == 1) {
    float lsum = 0.0f, lssq = 0.0f;
#pragma unroll
    for (int mi = 0; mi < 4; ++mi) {
      int gm = bm + wm + mi * 16 + quad * 4;
#pragma unroll
      for (int ni = 0; ni < 2; ++ni) {
        int gn = bn + wn + ni * 16 + r16;
        if (gn < Nreal) {
          float bv = bias[gn];
#pragma unroll
          for (int r = 0; r < 4; ++r) {
            float v = acc[mi][ni][r] + bv;
            v = (v >= 0.0f) ? v : 0.01f * v;
            C[(size_t)(gm + r) * ldc + gn] = v;
            lsum += v;
            lssq += v * v;
          }
        }
      }
    }
    red[tid] = lsum;
    __syncthreads();
    for (int off = 256; off > 0; off >>= 1) {
      if (tid < off) red[tid] += red[tid + off];
      __syncthreads();
    }
    if (tid == 0) atomicAdd(&st0[seg], red[0]);
    __syncthreads();
    red[tid] = lssq;
    __syncthreads();
    for (int off = 256; off > 0; off >>= 1) {
      if (tid < off) red[tid] += red[tid + off];
      __syncthreads();
    }
    if (tid == 0) atomicAdd(&st1[seg], red[0]);
  } else if (mode == 2) {
    if (tid < 128) { cs[tid] = 0.0f; css[tid] = 0.0f; }
    __syncthreads();
#pragma unroll
    for (int ni = 0; ni < 2; ++ni) {
      int col = wn + ni * 16 + r16;       // 0..127
      int gn = bn + col;
      float bv = bias[gn];
      float psum = 0.0f, pssq = 0.0f;
#pragma unroll
      for (int mi = 0; mi < 4; ++mi) {
        int gm = bm + wm + mi * 16 + quad * 4;
#pragma unroll
        for (int r = 0; r < 4; ++r) {
          float v = acc[mi][ni][r] + bv;
          C[(size_t)(gm + r) * ldc + gn] = v;
          psum += v;
          pssq += v * v;
        }
      }
      atomicAdd(&cs[col], psum);
      atomicAdd(&css[col], pssq);
    }
    __syncthreads();
    if (tid < 128) {
      atomicAdd(&st0[bn + tid], cs[tid]);
      atomicAdd(&st1[bn + tid], css[tid]);
    }
  } else {
    // mode 3: pooled head — outp[seg] += sum_rows dot(acc+bias, wc)
    float part = 0.0f;
#pragma unroll
    for (int ni = 0; ni < 2; ++ni) {
      int gn = bn + wn + ni * 16 + r16;
      float bv = bias[gn];
      float wv = wcp[gn];
      float colsum = 0.0f;
#pragma unroll
      for (int mi = 0; mi < 4; ++mi)
#pragma unroll
        for (int r = 0; r < 4; ++r)
          colsum += acc[mi][ni][r] + bv;
      part += colsum * wv;
    }
    red[tid] = part;
    __syncthreads();
    for (int off = 256; off > 0; off >>= 1) {
      if (tid < off) red[tid] += red[tid + off];
      __syncthreads();
    }
    if (tid == 0) atomicAdd(&outp[seg], red[0]);
  }
}

// ---------------------------------------------------------------------------
// GLN apply, vectorized: float4 in -> uint2 (4 bf16) out.
// ---------------------------------------------------------------------------
__global__ __launch_bounds__(256) void gln_apply_v(
    const float* __restrict__ x, int D, int Dp, int lanes4, int rpb,
    const float* __restrict__ seg_sum, const float* __restrict__ seg_ssq,
    const float* __restrict__ g, const float* __restrict__ be,
    unsigned short* __restrict__ out, int ldo, int co) {
  int tid = threadIdx.x;
  int ri = tid / lanes4;
  if (ri >= rpb) return;
  int f4 = tid - ri * lanes4;
  int r = blockIdx.x * rpb + ri;
  int s = r >> 8;
  float cnt = 256.0f * (float)D;
  float m = seg_sum[s] / cnt;
  float var = seg_ssq[s] / cnt - m * m;
  float inv = rsqrtf(var + 1e-5f);
  int c0 = f4 * 4;
  float4 v = ((const float4*)(x + (size_t)r * Dp))[f4];
  float o0 = (c0 + 0 < D) ? ((v.x - m) * inv * g[c0 + 0] + be[c0 + 0]) : 0.0f;
  float o1 = (c0 + 1 < D) ? ((v.y - m) * inv * g[c0 + 1] + be[c0 + 1]) : 0.0f;
  float o2 = (c0 + 2 < D) ? ((v.z - m) * inv * g[c0 + 2] + be[c0 + 2]) : 0.0f;
  float o3 = (c0 + 3 < D) ? ((v.w - m) * inv * g[c0 + 3] + be[c0 + 3]) : 0.0f;
  uint2 o;
  o.x = pack2(o0, o1);
  o.y = pack2(o2, o3);
  ((uint2*)(out + (size_t)r * ldo + co))[f4] = o;
}

// ---------------------------------------------------------------------------
// neighbor-mean aggregation: uint4 (8 bf16 = 16B) per lane, edge loop x4.
// Per-accumulator add order = edge order (bitwise identical to unrolled-1).
// ---------------------------------------------------------------------------
__device__ __forceinline__ void acc8(uint4 v, float& a0, float& a1, float& a2,
                                     float& a3, float& a4, float& a5,
                                     float& a6, float& a7) {
  a0 += bf2f(v.x & 0xffffu); a1 += bf2f(v.x >> 16);
  a2 += bf2f(v.y & 0xffffu); a3 += bf2f(v.y >> 16);
  a4 += bf2f(v.z & 0xffffu); a5 += bf2f(v.z >> 16);
  a6 += bf2f(v.w & 0xffffu); a7 += bf2f(v.w >> 16);
}

__global__ __launch_bounds__(256) void aggregate8(
    const unsigned short* __restrict__ xs, int ldu4, int cb4, int cba4, int L8,
    unsigned short* __restrict__ aggs,
    const int* __restrict__ offsets, const int* __restrict__ srcs,
    const float* __restrict__ inv_deg) {
  int tid = threadIdx.x;
  int n = (blockIdx.x << (8 - L8)) + (tid >> L8);
  int f8 = tid & ((1 << L8) - 1);
  int start = offsets[n], end = offsets[n + 1];
  float wgt = inv_deg[n];
  const uint4* xb = (const uint4*)xs;
  float a0 = 0, a1 = 0, a2 = 0, a3 = 0, a4 = 0, a5 = 0, a6 = 0, a7 = 0;
  int e = start;
  for (; e + 4 <= end; e += 4) {
    uint4 v0 = xb[(size_t)srcs[e] * ldu4 + cb4 + f8];
    uint4 v1 = xb[(size_t)srcs[e + 1] * ldu4 + cb4 + f8];
    uint4 v2 = xb[(size_t)srcs[e + 2] * ldu4 + cb4 + f8];
    uint4 v3 = xb[(size_t)srcs[e + 3] * ldu4 + cb4 + f8];
    acc8(v0, a0, a1, a2, a3, a4, a5, a6, a7);
    acc8(v1, a0, a1, a2, a3, a4, a5, a6, a7);
    acc8(v2, a0, a1, a2, a3, a4, a5, a6, a7);
    acc8(v3, a0, a1, a2, a3, a4, a5, a6, a7);
  }
  for (; e < end; ++e) {
    uint4 v = xb[(size_t)srcs[e] * ldu4 + cb4 + f8];
    acc8(v, a0, a1, a2, a3, a4, a5, a6, a7);
  }
  uint4 o;
  o.x = pack2(a0 * wgt, a1 * wgt);
  o.y = pack2(a2 * wgt, a3 * wgt);
  o.z = pack2(a4 * wgt, a5 * wgt);
  o.w = pack2(a6 * wgt, a7 * wgt);
  ((uint4*)aggs)[(size_t)n * ldu4 + cba4 + f8] = o;
}

// ---------------------------------------------------------------------------
// PairNorm finalize (single tiny dispatch) + vectorized apply (+ReLU)
// ---------------------------------------------------------------------------
__global__ __launch_bounds__(512) void pn_finalize(const float* __restrict__ colsum,
                                                   const float* __restrict__ colssq,
                                                   float* __restrict__ mu,
                                                   float* __restrict__ invd) {
  int f = threadIdx.x;
  float m = colsum[f] / (float)NN;
  mu[f] = m;
  float t = colssq[f] / (float)NN - m * m;
  __shared__ float buf[512];
  buf[f] = t;
  __syncthreads();
  for (int off = 256; off > 0; off >>= 1) {
    if (f < off) buf[f] += buf[f + off];
    __syncthreads();
  }
  if (f == 0) invd[0] = 1.0f / (1e-5f + sqrtf(fmaxf(buf[0], 0.0f)));
}

__global__ __launch_bounds__(256) void pn_apply_v(const float* __restrict__ y,
                                                  const float* __restrict__ mu,
                                                  const float* __restrict__ invd,
                                                  unsigned short* __restrict__ xb,
                                                  int ldou2, int cou2) {
  int t = threadIdx.x;
  int r = blockIdx.x * 2 + (t >> 7);
  int f4 = t & 127;
  float id = invd[0];
  float4 v = ((const float4*)(y + (size_t)r * GH_))[f4];
  float4 m = ((const float4*)mu)[f4];
  float v0 = fmaxf((v.x - m.x) * id, 0.0f);
  float v1 = fmaxf((v.y - m.y) * id, 0.0f);
  float v2 = fmaxf((v.z - m.z) * id, 0.0f);
  float v3 = fmaxf((v.w - m.w) * id, 0.0f);
  uint2 o;
  o.x = pack2(v0, v1);
  o.y = pack2(v2, v3);
  ((uint2*)xb)[(size_t)r * ldou2 + cou2 + f4] = o;
}

// ---------------------------------------------------------------------------
extern "C" void kernel_launch(void* const* d_in, const int* in_sizes, int n_in,
                              void* d_out, int out_size, void* d_ws, size_t ws_size,
                              hipStream_t stream) {
  const float* node_features = (const float*)d_in[0];
  const float* node_config   = (const float*)d_in[1];
  const float* emb_table     = (const float*)d_in[2];
  const float* w1  = (const float*)d_in[3];
  const float* b1  = (const float*)d_in[4];
  const float* g1  = (const float*)d_in[5];
  const float* be1 = (const float*)d_in[6];
  const float* w2  = (const float*)d_in[7];
  const float* b2  = (const float*)d_in[8];
  const float* g2  = (const float*)d_in[9];
  const float* be2 = (const float*)d_in[10];
  const float* wl1 = (const float*)d_in[11];
  const float* bl1 = (const float*)d_in[12];
  const float* wr1 = (const float*)d_in[13];
  const float* wl2 = (const float*)d_in[14];
  const float* bl2 = (const float*)d_in[15];
  const float* wr2 = (const float*)d_in[16];
  const float* wl3 = (const float*)d_in[17];
  const float* bl3 = (const float*)d_in[18];
  const float* wr3 = (const float*)d_in[19];
  const float* wc  = (const float*)d_in[20];
  const float* bc  = (const float*)d_in[21];
  const int* node_ops = (const int*)d_in[22];
  const int* edges    = (const int*)d_in[23];
  float* out = (float*)d_out;

  char* ws = (char*)d_ws;
  size_t off = 0;
  auto alloc = [&](size_t bytes) -> void* {
    void* p = ws + off;
    off += (bytes + 255) & ~(size_t)255;
    return p;
  };

  // deg_i + cursor contiguous -> single memset
  int*   deg_i   = (int*)alloc(NN * 4);
  int*   cursor  = (int*)alloc(NN * 4);
  int*   offsets = (int*)alloc((NN + 1) * 4);
  int*   srcs    = (int*)alloc(EE * 4);
  int*   bsum    = (int*)alloc(SS * 4);
  int*   boff    = (int*)alloc(SS * 4);
  float* inv_deg = (float*)alloc(NN * 4);
  float* stat_all= (float*)alloc(2560 * 4);
  float* mu      = (float*)alloc(512 * 4);
  float* invd    = (float*)alloc(256);
  // bf16 weights (padded / packed)
  unsigned short* w1b = (unsigned short*)alloc((size_t)384 * 192 * 2);
  unsigned short* w2b = (unsigned short*)alloc((size_t)256 * 384 * 2);
  unsigned short* wc1 = (unsigned short*)alloc((size_t)512 * 512 * 2);
  unsigned short* wc2 = (unsigned short*)alloc((size_t)512 * 1024 * 2);
  unsigned short* wc3 = (unsigned short*)alloc((size_t)512 * 1024 * 2);
  // activations
  unsigned short* X0  = (unsigned short*)alloc((size_t)NN * 192 * 2);   // 12.6 MB
  unsigned short* H1  = (unsigned short*)alloc((size_t)NN * 384 * 2);   // 25.2 MB
  unsigned short* XC1 = (unsigned short*)alloc((size_t)NN * 512 * 2);   // [agg1|h2] 33.5 MB
  unsigned short* XC2 = (unsigned short*)alloc((size_t)NN * 1024 * 2);  // [agg|x] 67 MB
  float*          Y   = (float*)alloc((size_t)NN * 512 * 4);            // 67 MB

  const int* esrc = edges;
  const int* edst = edges + EE;

  // stat_all regions: gln1 s[0,128) q[128,256) | gln2 s[256,384) q[384,512)
  //                   pn1 cs0[512,1024) cs1[1024,1536) | pn2 cs0[1536,2048) cs1[2048,2560)
  float* gln1s = stat_all;        float* gln1q = stat_all + 128;
  float* gln2s = stat_all + 256;  float* gln2q = stat_all + 384;
  float* pn1s  = stat_all + 512;  float* pn1q  = stat_all + 1024;
  float* pn2s  = stat_all + 1536; float* pn2q  = stat_all + 2048;

  // ---- zero deg + cursor (one memset) ----
  hipMemsetAsync(deg_i, 0, (size_t)NN * 4 * 2, stream);

  // ---- CSR build ----
  deg_count<<<EE / 256, 256, 0, stream>>>(edst, deg_i);
  blk_sum_k<<<NN / 256, 256, 0, stream>>>(deg_i, bsum);
  blk_scan_k<<<1, 128, 0, stream>>>(bsum, boff);
  offsets_k<<<NN / 256, 256, 0, stream>>>(deg_i, boff, offsets, inv_deg);
  bucket_k<<<EE / 256, 256, 0, stream>>>(esrc, edst, offsets, cursor, srcs);

  // ---- prep: stats zero, out init, weights, x0 ----
  prep_all<<<4096, 256, 0, stream>>>(node_features, node_config, emb_table, node_ops,
                                     w1, w2, wl1, wr1, wl2, wr2, wl3, wr3,
                                     w1b, w2b, wc1, wc2, wc3,
                                     X0, stat_all, out, bc);

  // ---- MLP layer 1: Y = leaky(x0@w1^T+b1) + GLN stats; apply -> H1 ----
  {
    dim3 g(3, 256);
    mfma_gemm<<<g, 512, 0, stream>>>(X0, 192, w1b, 192, 192,
                                     b1, Y, 384, DX_, 1, 0,
                                     gln1s, gln1q, nullptr, nullptr);
  }
  gln_apply_v<<<NN / 2, 256, 0, stream>>>(Y, DX_, 384, 96, 2, gln1s, gln1q,
                                          g1, be1, H1, 384, 0);

  // ---- MLP layer 2: Y = leaky(h1@w2^T+b2) + GLN stats; apply -> XC1 cols[256,512) ----
  {
    dim3 g(2, 256);
    mfma_gemm<<<g, 512, 0, stream>>>(H1, 384, w2b, 384, 384,
                                     b2, Y, 256, GIN_, 1, 0,
                                     gln2s, gln2q, nullptr, nullptr);
  }
  gln_apply_v<<<NN / 4, 256, 0, stream>>>(Y, GIN_, 256, 64, 4, gln2s, gln2q,
                                          g2, be2, XC1, 512, 256);

  // ---- SAGE 1: agg1 -> XC1 cols[0,256); Y = XC1 @ WC1^T (+col stats) ----
  aggregate8<<<NN / 8, 256, 0, stream>>>(XC1, 64, 32, 0, 5, XC1,
                                         offsets, srcs, inv_deg);
  mfma_gemm<<<1024, 512, 0, stream>>>(XC1, 512, wc1, 512, 512,
                                      bl1, Y, 512, GH_, 2, 1,
                                      pn1s, pn1q, nullptr, nullptr);
  pn_finalize<<<1, 512, 0, stream>>>(pn1s, pn1q, mu, invd);
  pn_apply_v<<<NN / 2, 256, 0, stream>>>(Y, mu, invd, XC2, 256, 128);  // x1 -> XC2 cols[512,1024)

  // ---- SAGE 2: agg2 -> XC2 cols[0,512); Y = XC2 @ WC2^T (+col stats) ----
  aggregate8<<<NN / 4, 256, 0, stream>>>(XC2, 128, 64, 0, 6, XC2,
                                         offsets, srcs, inv_deg);
  mfma_gemm<<<1024, 512, 0, stream>>>(XC2, 1024, wc2, 1024, 1024,
                                      bl2, Y, 512, GH_, 2, 1,
                                      pn2s, pn2q, nullptr, nullptr);
  pn_finalize<<<1, 512, 0, stream>>>(pn2s, pn2q, mu, invd);
  pn_apply_v<<<NN / 2, 256, 0, stream>>>(Y, mu, invd, XC2, 256, 128);  // x2 overwrites x1

  // ---- SAGE 3 + head: agg3 -> XC2 cols[0,512); out[seg] += pooled head ----
  aggregate8<<<NN / 4, 256, 0, stream>>>(XC2, 128, 64, 0, 6, XC2,
                                         offsets, srcs, inv_deg);
  mfma_gemm<<<1024, 512, 0, stream>>>(XC2, 1024, wc3, 1024, 1024,
                                      bl3, nullptr, 512, GH_, 3, 1,
                                      nullptr, nullptr, wc, out);
}

// Round 11
// 594.129 us; speedup vs baseline: 1.0246x; 1.0246x over previous
//
#include <hip/hip_runtime.h>
#include <hip/hip_bf16.h>

// ---- problem constants (fixed by setup_inputs) ----
#define NN   32768
#define EE   262144
#define SS   128
#define NF_  90
#define NC_  36
#define OD_  64
#define D0_  190
#define DX_  380
#define GIN_ 256
#define GH_  512

typedef __attribute__((ext_vector_type(8))) short  s8v;   // 8 bf16 = 4 VGPRs
typedef __attribute__((ext_vector_type(4))) float  f4v;   // 4 fp32

typedef const __attribute__((address_space(1))) void* gas_ptr;
typedef __attribute__((address_space(3))) void*       las_ptr;

// ---- bf16 helpers (manual, RN) ----
__device__ __forceinline__ float bf2f(unsigned u) {
  return __uint_as_float(u << 16);
}
__device__ __forceinline__ unsigned short f2bf(float f) {
  unsigned u = __float_as_uint(f);
  u += 0x7FFFu + ((u >> 16) & 1u);
  return (unsigned short)(u >> 16);
}
__device__ __forceinline__ unsigned pack2(float a, float b) {
  return ((unsigned)f2bf(b) << 16) | (unsigned)f2bf(a);
}

// ---------------------------------------------------------------------------
// degree / CSR build (parallel 3-phase scan)
// ---------------------------------------------------------------------------
__global__ void deg_count(const int* __restrict__ dst, int* __restrict__ deg) {
  int e = blockIdx.x * 256 + threadIdx.x;
  if (e < EE) atomicAdd(&deg[dst[e]], 1);
}

__global__ __launch_bounds__(256) void blk_sum_k(const int* __restrict__ deg,
                                                 int* __restrict__ bsum) {
  __shared__ int buf[256];
  int tid = threadIdx.x;
  buf[tid] = deg[blockIdx.x * 256 + tid];
  __syncthreads();
  for (int off = 128; off > 0; off >>= 1) {
    if (tid < off) buf[tid] += buf[tid + off];
    __syncthreads();
  }
  if (tid == 0) bsum[blockIdx.x] = buf[0];
}

__global__ __launch_bounds__(128) void blk_scan_k(const int* __restrict__ bsum,
                                                  int* __restrict__ boff) {
  __shared__ int buf[128];
  int tid = threadIdx.x;
  int v = bsum[tid];
  buf[tid] = v;
  __syncthreads();
  for (int d = 1; d < 128; d <<= 1) {
    int t = (tid >= d) ? buf[tid - d] : 0;
    __syncthreads();
    if (tid >= d) buf[tid] += t;
    __syncthreads();
  }
  boff[tid] = buf[tid] - v;   // exclusive
}

__global__ __launch_bounds__(256) void offsets_k(const int* __restrict__ deg,
                                                 const int* __restrict__ boff,
                                                 int* __restrict__ offsets,
                                                 float* __restrict__ inv_deg) {
  __shared__ int buf[256];
  int tid = threadIdx.x;
  int i = blockIdx.x * 256 + tid;
  int v = deg[i];
  buf[tid] = v;
  __syncthreads();
  for (int d = 1; d < 256; d <<= 1) {
    int t = (tid >= d) ? buf[tid - d] : 0;
    __syncthreads();
    if (tid >= d) buf[tid] += t;
    __syncthreads();
  }
  offsets[i] = boff[blockIdx.x] + buf[tid] - v;
  inv_deg[i] = 1.0f / fmaxf((float)v, 1.0f);
  if (i == 0) offsets[NN] = EE;
}

__global__ void bucket_k(const int* __restrict__ src, const int* __restrict__ dst,
                         const int* __restrict__ offsets, int* __restrict__ cursor,
                         int* __restrict__ srcs) {
  int e = blockIdx.x * 256 + threadIdx.x;
  if (e < EE) {
    int d = dst[e];
    int pos = offsets[d] + atomicAdd(&cursor[d], 1);
    srcs[pos] = src[e];
  }
}

// ---------------------------------------------------------------------------
// prep_all: zero stats, init out, convert+pack all weights to bf16, build x0
// packed SAGE weights: WC[j] = [wl[j] | wr[j]]
// ---------------------------------------------------------------------------
#define P1 73728          // w1b  [384x192]
#define P2 172032         // w2b  [256x384]
#define P3 434176         // WC1  [512x512]
#define P4 958464         // WC2  [512x1024]
#define P5 1482752        // WC3  [512x1024]

__global__ __launch_bounds__(256) void prep_all(
    const float* __restrict__ nf, const float* __restrict__ ncf,
    const float* __restrict__ emb, const int* __restrict__ ops,
    const float* __restrict__ w1, const float* __restrict__ w2,
    const float* __restrict__ wl1, const float* __restrict__ wr1,
    const float* __restrict__ wl2, const float* __restrict__ wr2,
    const float* __restrict__ wl3, const float* __restrict__ wr3,
    unsigned short* __restrict__ w1b, unsigned short* __restrict__ w2b,
    unsigned short* __restrict__ wc1, unsigned short* __restrict__ wc2,
    unsigned short* __restrict__ wc3,
    unsigned short* __restrict__ x0,
    float* __restrict__ stat_all, float* __restrict__ outp,
    const float* __restrict__ bc)
{
  const int T = 4096 * 256;
  int gidx = blockIdx.x * 256 + threadIdx.x;
  for (int i = gidx; i < 2560; i += T) stat_all[i] = 0.0f;
  if (gidx < SS) outp[gidx] = bc[0];
  for (int i = gidx; i < P5; i += T) {
    if (i < P1) {
      int r = i / 192, c = i - r * 192;
      w1b[i] = f2bf((r < DX_ && c < D0_) ? w1[r * D0_ + c] : 0.0f);
    } else if (i < P2) {
      int j = i - P1;
      int r = j / 384, c = j - r * 384;
      w2b[j] = f2bf((c < DX_) ? w2[r * DX_ + c] : 0.0f);
    } else if (i < P3) {
      int j = i - P2;                 // [0, 512*512)
      int r = j >> 9, c = j & 511;
      wc1[j] = f2bf((c < 256) ? wl1[r * 256 + c] : wr1[r * 256 + (c - 256)]);
    } else if (i < P4) {
      int j = i - P3;                 // [0, 512*1024)
      int r = j >> 10, c = j & 1023;
      wc2[j] = f2bf((c < 512) ? wl2[r * 512 + c] : wr2[r * 512 + (c - 512)]);
    } else {
      int j = i - P4;
      int r = j >> 10, c = j & 1023;
      wc3[j] = f2bf((c < 512) ? wl3[r * 512 + c] : wr3[r * 512 + (c - 512)]);
    }
  }
  for (int i = gidx; i < NN * 192; i += T) {
    int n = i / 192;
    int c = i - n * 192;
    float v;
    if (c < NF_)            v = nf[n * NF_ + c];
    else if (c < NF_ + NC_) v = ncf[n * NC_ + (c - NF_)];
    else if (c < D0_)       v = emb[ops[n] * OD_ + (c - (NF_ + NC_))];
    else                    v = 0.0f;
    x0[i] = f2bf(v);
  }
}

// ---------------------------------------------------------------------------
// bf16 MFMA GEMM (NT), single-phase, BK=64: acc = A*B^T
// 128x128 tile, 256 thr = 4 waves (2x2), each wave 64x64 via 4x4 mfma 16x16x32.
// LDS: [koff(8)][row(128)][8 bf16] per matrix = 16 KB each, 32 KB total.
// C-write: transposed through LDS scratch -> fully coalesced float4 stores
// (the naive per-lane strided write was the measured wall at ~0.7 TB/s).
// mode 1: C=leaky(acc+bias) fp32, fused scalar (GLN) stats -> st0/st1[seg]
// mode 2: C=acc+bias fp32, fused column (PairNorm) stats -> st0/st1[col]
// mode 3: no C write; outp[seg] += sum_rows dot(acc+bias, wcp)
// swz=1: 1D grid 1024, XCD-aware decode keeping same-bm tiles on one XCD.
// ---------------------------------------------------------------------------
__device__ __forceinline__ void stage64(const unsigned short* __restrict__ G, int ld,
                                        int base_row, int k0,
                                        unsigned short* __restrict__ lds, int tid) {
#pragma unroll
  for (int i = 0; i < 4; ++i) {
    int c = tid + i * 256;        // 0..1023
    int row = c & 127;
    int koff = c >> 7;            // 0..7 (k chunk of 8 bf16)
    const unsigned short* src = G + (size_t)(base_row + row) * ld + k0 + koff * 8;
    unsigned short* dst = lds + koff * 1024 + row * 8;
    __builtin_amdgcn_global_load_lds((gas_ptr)(const void*)src, (las_ptr)(void*)dst,
                                     16, 0, 0);
  }
}

__global__ __launch_bounds__(256) void mfma_gemm(
    const unsigned short* __restrict__ A, int lda,
    const unsigned short* __restrict__ B, int ldb, int K,
    const float* __restrict__ bias,
    float* __restrict__ C, int ldc, int Nreal, int mode, int swz,
    float* __restrict__ st0, float* __restrict__ st1,
    const float* __restrict__ wcp, float* __restrict__ outp)
{
  __shared__ char smem[32768];
  unsigned short* As = (unsigned short*)smem;
  unsigned short* Bs = (unsigned short*)(smem + 16384);
  int tid = threadIdx.x;
  int lane = tid & 63;
  int w = tid >> 6;
  int wm = (w & 1) * 64;
  int wn = (w >> 1) * 64;
  int bm, bn;
  if (swz) {
    int L = blockIdx.x;
    int xcd = L & 7;
    int s = L >> 3;
    bn = (s & 3) * 128;
    bm = ((s >> 2) * 8 + xcd) * 128;
  } else {
    bm = blockIdx.y * 128;
    bn = blockIdx.x * 128;
  }
  int quad = lane >> 4;      // 0..3
  int r16 = lane & 15;

  f4v acc[4][4] = {};

  for (int k0 = 0; k0 < K; k0 += 64) {
    stage64(A, lda, bm, k0, As, tid);
    stage64(B, ldb, bn, k0, Bs, tid);
    __syncthreads();
#pragma unroll
    for (int s = 0; s < 2; ++s) {
      s8v af[4], bfr[4];
#pragma unroll
      for (int mi = 0; mi < 4; ++mi)
        af[mi] = *(const s8v*)&As[(s * 4 + quad) * 1024 + (wm + mi * 16 + r16) * 8];
#pragma unroll
      for (int ni = 0; ni < 4; ++ni)
        bfr[ni] = *(const s8v*)&Bs[(s * 4 + quad) * 1024 + (wn + ni * 16 + r16) * 8];
#pragma unroll
      for (int mi = 0; mi < 4; ++mi)
#pragma unroll
        for (int ni = 0; ni < 4; ++ni)
          acc[mi][ni] = __builtin_amdgcn_mfma_f32_16x16x32_bf16(
              af[mi], bfr[ni], acc[mi][ni], 0, 0, 0);
    }
    __syncthreads();
  }

  float* scr = (float*)smem;          // 8192 floats of epilogue scratch
  int seg = bm >> 8;

  if (mode == 1) {
    // v = leaky(acc+bias) back into acc (0 in pad cols); scalar GLN stats
    float lsum = 0.0f, lssq = 0.0f;
#pragma unroll
    for (int mi = 0; mi < 4; ++mi) {
#pragma unroll
      for (int ni = 0; ni < 4; ++ni) {
        int gn = bn + wn + ni * 16 + r16;
        float bv = (gn < Nreal) ? bias[gn] : 0.0f;
#pragma unroll
        for (int r = 0; r < 4; ++r) {
          float v = 0.0f;
          if (gn < Nreal) {
            v = acc[mi][ni][r] + bv;
            v = (v >= 0.0f) ? v : 0.01f * v;
            lsum += v;
            lssq += v * v;
          }
          acc[mi][ni][r] = v;
        }
      }
    }
    scr[tid] = lsum;
    __syncthreads();
    for (int off = 128; off > 0; off >>= 1) {
      if (tid < off) scr[tid] += scr[tid + off];
      __syncthreads();
    }
    if (tid == 0) atomicAdd(&st0[seg], scr[0]);
    __syncthreads();
    scr[tid] = lssq;
    __syncthreads();
    for (int off = 128; off > 0; off >>= 1) {
      if (tid < off) scr[tid] += scr[tid + off];
      __syncthreads();
    }
    if (tid == 0) atomicAdd(&st1[seg], scr[0]);
  } else if (mode == 2) {
    // v = acc + bias back into acc; per-column PairNorm stats
    float* cs  = scr;
    float* css = scr + 128;
    if (tid < 128) { cs[tid] = 0.0f; css[tid] = 0.0f; }
    __syncthreads();
#pragma unroll
    for (int ni = 0; ni < 4; ++ni) {
      int col = wn + ni * 16 + r16;       // 0..127
      float bv = bias[bn + col];
      float psum = 0.0f, pssq = 0.0f;
#pragma unroll
      for (int mi = 0; mi < 4; ++mi) {
#pragma unroll
        for (int r = 0; r < 4; ++r) {
          float v = acc[mi][ni][r] + bv;
          acc[mi][ni][r] = v;
          psum += v;
          pssq += v * v;
        }
      }
      atomicAdd(&cs[col], psum);
      atomicAdd(&css[col], pssq);
    }
    __syncthreads();
    if (tid < 128) {
      atomicAdd(&st0[bn + tid], cs[tid]);
      atomicAdd(&st1[bn + tid], css[tid]);
    }
  } else {
    // mode 3: pooled head — outp[seg] += sum_rows dot(acc+bias, wc); no C write
    float part = 0.0f;
#pragma unroll
    for (int ni = 0; ni < 4; ++ni) {
      int gn = bn + wn + ni * 16 + r16;
      float bv = bias[gn];
      float wv = wcp[gn];
      float colsum = 0.0f;
#pragma unroll
      for (int mi = 0; mi < 4; ++mi)
#pragma unroll
        for (int r = 0; r < 4; ++r)
          colsum += acc[mi][ni][r] + bv;
      part += colsum * wv;
    }
    scr[tid] = part;
    __syncthreads();
    for (int off = 128; off > 0; off >>= 1) {
      if (tid < off) scr[tid] += scr[tid + off];
      __syncthreads();
    }
    if (tid == 0) atomicAdd(&outp[seg], scr[0]);
    return;
  }

  // ---- transposed coalesced C write: 2 halves of 64 rows x 128 cols ----
#pragma unroll
  for (int h = 0; h < 2; ++h) {
    __syncthreads();
    if (wm == h * 64) {
      // the 2 waves owning this half scatter their acc into scratch
#pragma unroll
      for (int mi = 0; mi < 4; ++mi) {
#pragma unroll
        for (int ni = 0; ni < 4; ++ni) {
          int lcol = wn + ni * 16 + r16;        // 0..127
#pragma unroll
          for (int r = 0; r < 4; ++r) {
            int lrow = mi * 16 + quad * 4 + r;  // 0..63
            scr[lrow * 128 + lcol] = acc[mi][ni][r];
          }
        }
      }
    }
    __syncthreads();
    // all 256 threads stream out as float4 (fully coalesced)
#pragma unroll
    for (int it = 0; it < 8; ++it) {
      int idx = tid + it * 256;                 // 0..2047
      int lrow = idx >> 5;
      int c4 = idx & 31;
      float4 val = ((const float4*)scr)[idx];
      ((float4*)(C + (size_t)(bm + h * 64 + lrow) * ldc + bn))[c4] = val;
    }
  }
}

// ---------------------------------------------------------------------------
// GLN apply (finalize folded in): Y fp32 -> bf16, written at column offset co
// ---------------------------------------------------------------------------
__global__ __launch_bounds__(256) void gln_apply_bf16(
    const float* __restrict__ x, int ld, int D, int Dp,
    const float* __restrict__ seg_sum, const float* __restrict__ seg_ssq,
    const float* __restrict__ g, const float* __restrict__ be,
    unsigned short* __restrict__ out, int ldo, int co) {
  int r = blockIdx.x;
  int s = r >> 8;
  float cnt = 256.0f * (float)D;
  float m = seg_sum[s] / cnt;
  float var = seg_ssq[s] / cnt - m * m;
  float inv = rsqrtf(var + 1e-5f);
  const float* row = x + (size_t)r * ld;
  unsigned short* orow = out + (size_t)r * ldo + co;
  for (int c = threadIdx.x; c < Dp; c += 256) {
    float v = (c < D) ? ((row[c] - m) * inv * g[c] + be[c]) : 0.0f;
    orow[c] = f2bf(v);
  }
}

// ---------------------------------------------------------------------------
// neighbor-mean aggregation: uint4 (8 bf16 = 16B) per lane, edge loop x2.
// ---------------------------------------------------------------------------
__device__ __forceinline__ void acc8(uint4 v, float& a0, float& a1, float& a2,
                                     float& a3, float& a4, float& a5,
                                     float& a6, float& a7) {
  a0 += bf2f(v.x & 0xffffu); a1 += bf2f(v.x >> 16);
  a2 += bf2f(v.y & 0xffffu); a3 += bf2f(v.y >> 16);
  a4 += bf2f(v.z & 0xffffu); a5 += bf2f(v.z >> 16);
  a6 += bf2f(v.w & 0xffffu); a7 += bf2f(v.w >> 16);
}

__global__ __launch_bounds__(256) void aggregate8(
    const unsigned short* __restrict__ xs, int ldu4, int cb4, int cba4, int L8,
    unsigned short* __restrict__ aggs,
    const int* __restrict__ offsets, const int* __restrict__ srcs,
    const float* __restrict__ inv_deg) {
  int tid = threadIdx.x;
  int n = (blockIdx.x << (8 - L8)) + (tid >> L8);
  int f8 = tid & ((1 << L8) - 1);
  int start = offsets[n], end = offsets[n + 1];
  float wgt = inv_deg[n];
  const uint4* xb = (const uint4*)xs;
  float a0 = 0, a1 = 0, a2 = 0, a3 = 0, a4 = 0, a5 = 0, a6 = 0, a7 = 0;
  int e = start;
  for (; e + 2 <= end; e += 2) {
    uint4 v0 = xb[(size_t)srcs[e] * ldu4 + cb4 + f8];
    uint4 v1 = xb[(size_t)srcs[e + 1] * ldu4 + cb4 + f8];
    acc8(v0, a0, a1, a2, a3, a4, a5, a6, a7);
    acc8(v1, a0, a1, a2, a3, a4, a5, a6, a7);
  }
  if (e < end) {
    uint4 v = xb[(size_t)srcs[e] * ldu4 + cb4 + f8];
    acc8(v, a0, a1, a2, a3, a4, a5, a6, a7);
  }
  uint4 o;
  o.x = pack2(a0 * wgt, a1 * wgt);
  o.y = pack2(a2 * wgt, a3 * wgt);
  o.z = pack2(a4 * wgt, a5 * wgt);
  o.w = pack2(a6 * wgt, a7 * wgt);
  ((uint4*)aggs)[(size_t)n * ldu4 + cba4 + f8] = o;
}

// ---------------------------------------------------------------------------
// PairNorm finalize + vectorized apply (float4 in, uint2 out, +ReLU)
// ---------------------------------------------------------------------------
__global__ __launch_bounds__(512) void pn_finalize(const float* __restrict__ colsum,
                                                   const float* __restrict__ colssq,
                                                   float* __restrict__ mu,
                                                   float* __restrict__ invd) {
  int f = threadIdx.x;
  float m = colsum[f] / (float)NN;
  mu[f] = m;
  float t = colssq[f] / (float)NN - m * m;
  __shared__ float buf[512];
  buf[f] = t;
  __syncthreads();
  for (int off = 256; off > 0; off >>= 1) {
    if (f < off) buf[f] += buf[f + off];
    __syncthreads();
  }
  if (f == 0) invd[0] = 1.0f / (1e-5f + sqrtf(fmaxf(buf[0], 0.0f)));
}

__global__ __launch_bounds__(256) void pn_apply_v(const float* __restrict__ y,
                                                  const float* __restrict__ mu,
                                                  const float* __restrict__ invd,
                                                  unsigned short* __restrict__ xb,
                                                  int ldou2, int cou2) {
  int t = threadIdx.x;
  int r = blockIdx.x * 2 + (t >> 7);
  int f4 = t & 127;
  float id = invd[0];
  float4 v = ((const float4*)(y + (size_t)r * GH_))[f4];
  float4 m = ((const float4*)mu)[f4];
  float v0 = fmaxf((v.x - m.x) * id, 0.0f);
  float v1 = fmaxf((v.y - m.y) * id, 0.0f);
  float v2 = fmaxf((v.z - m.z) * id, 0.0f);
  float v3 = fmaxf((v.w - m.w) * id, 0.0f);
  uint2 o;
  o.x = pack2(v0, v1);
  o.y = pack2(v2, v3);
  ((uint2*)xb)[(size_t)r * ldou2 + cou2 + f4] = o;
}

// ---------------------------------------------------------------------------
extern "C" void kernel_launch(void* const* d_in, const int* in_sizes, int n_in,
                              void* d_out, int out_size, void* d_ws, size_t ws_size,
                              hipStream_t stream) {
  const float* node_features = (const float*)d_in[0];
  const float* node_config   = (const float*)d_in[1];
  const float* emb_table     = (const float*)d_in[2];
  const float* w1  = (const float*)d_in[3];
  const float* b1  = (const float*)d_in[4];
  const float* g1  = (const float*)d_in[5];
  const float* be1 = (const float*)d_in[6];
  const float* w2  = (const float*)d_in[7];
  const float* b2  = (const float*)d_in[8];
  const float* g2  = (const float*)d_in[9];
  const float* be2 = (const float*)d_in[10];
  const float* wl1 = (const float*)d_in[11];
  const float* bl1 = (const float*)d_in[12];
  const float* wr1 = (const float*)d_in[13];
  const float* wl2 = (const float*)d_in[14];
  const float* bl2 = (const float*)d_in[15];
  const float* wr2 = (const float*)d_in[16];
  const float* wl3 = (const float*)d_in[17];
  const float* bl3 = (const float*)d_in[18];
  const float* wr3 = (const float*)d_in[19];
  const float* wc  = (const float*)d_in[20];
  const float* bc  = (const float*)d_in[21];
  const int* node_ops = (const int*)d_in[22];
  const int* edges    = (const int*)d_in[23];
  float* out = (float*)d_out;

  char* ws = (char*)d_ws;
  size_t off = 0;
  auto alloc = [&](size_t bytes) -> void* {
    void* p = ws + off;
    off += (bytes + 255) & ~(size_t)255;
    return p;
  };

  // deg_i + cursor contiguous -> single memset
  int*   deg_i   = (int*)alloc(NN * 4);
  int*   cursor  = (int*)alloc(NN * 4);
  int*   offsets = (int*)alloc((NN + 1) * 4);
  int*   srcs    = (int*)alloc(EE * 4);
  int*   bsum    = (int*)alloc(SS * 4);
  int*   boff    = (int*)alloc(SS * 4);
  float* inv_deg = (float*)alloc(NN * 4);
  float* stat_all= (float*)alloc(2560 * 4);
  float* mu      = (float*)alloc(512 * 4);
  float* invd    = (float*)alloc(256);
  // bf16 weights (padded / packed)
  unsigned short* w1b = (unsigned short*)alloc((size_t)384 * 192 * 2);
  unsigned short* w2b = (unsigned short*)alloc((size_t)256 * 384 * 2);
  unsigned short* wc1 = (unsigned short*)alloc((size_t)512 * 512 * 2);
  unsigned short* wc2 = (unsigned short*)alloc((size_t)512 * 1024 * 2);
  unsigned short* wc3 = (unsigned short*)alloc((size_t)512 * 1024 * 2);
  // activations
  unsigned short* X0  = (unsigned short*)alloc((size_t)NN * 192 * 2);   // 12.6 MB
  unsigned short* H1  = (unsigned short*)alloc((size_t)NN * 384 * 2);   // 25.2 MB
  unsigned short* XC1 = (unsigned short*)alloc((size_t)NN * 512 * 2);   // [agg1|h2] 33.5 MB
  unsigned short* XC2 = (unsigned short*)alloc((size_t)NN * 1024 * 2);  // [agg|x] 67 MB
  float*          Y   = (float*)alloc((size_t)NN * 512 * 4);            // 67 MB

  const int* esrc = edges;
  const int* edst = edges + EE;

  // stat_all regions: gln1 s[0,128) q[128,256) | gln2 s[256,384) q[384,512)
  //                   pn1 cs0[512,1024) cs1[1024,1536) | pn2 cs0[1536,2048) cs1[2048,2560)
  float* gln1s = stat_all;        float* gln1q = stat_all + 128;
  float* gln2s = stat_all + 256;  float* gln2q = stat_all + 384;
  float* pn1s  = stat_all + 512;  float* pn1q  = stat_all + 1024;
  float* pn2s  = stat_all + 1536; float* pn2q  = stat_all + 2048;

  // ---- zero deg + cursor (one memset) ----
  hipMemsetAsync(deg_i, 0, (size_t)NN * 4 * 2, stream);

  // ---- CSR build ----
  deg_count<<<EE / 256, 256, 0, stream>>>(edst, deg_i);
  blk_sum_k<<<NN / 256, 256, 0, stream>>>(deg_i, bsum);
  blk_scan_k<<<1, 128, 0, stream>>>(bsum, boff);
  offsets_k<<<NN / 256, 256, 0, stream>>>(deg_i, boff, offsets, inv_deg);
  bucket_k<<<EE / 256, 256, 0, stream>>>(esrc, edst, offsets, cursor, srcs);

  // ---- prep: stats zero, out init, weights, x0 ----
  prep_all<<<4096, 256, 0, stream>>>(node_features, node_config, emb_table, node_ops,
                                     w1, w2, wl1, wr1, wl2, wr2, wl3, wr3,
                                     w1b, w2b, wc1, wc2, wc3,
                                     X0, stat_all, out, bc);

  // ---- MLP layer 1: Y = leaky(x0@w1^T+b1) + GLN stats; apply -> H1 ----
  {
    dim3 g(3, 256);
    mfma_gemm<<<g, 256, 0, stream>>>(X0, 192, w1b, 192, 192,
                                     b1, Y, 384, DX_, 1, 0,
                                     gln1s, gln1q, nullptr, nullptr);
  }
  gln_apply_bf16<<<NN, 256, 0, stream>>>(Y, 384, DX_, 384, gln1s, gln1q, g1, be1,
                                         H1, 384, 0);

  // ---- MLP layer 2: Y = leaky(h1@w2^T+b2) + GLN stats; apply -> XC1 cols[256,512) ----
  {
    dim3 g(2, 256);
    mfma_gemm<<<g, 256, 0, stream>>>(H1, 384, w2b, 384, 384,
                                     b2, Y, 256, GIN_, 1, 0,
                                     gln2s, gln2q, nullptr, nullptr);
  }
  gln_apply_bf16<<<NN, 256, 0, stream>>>(Y, 256, GIN_, 256, gln2s, gln2q, g2, be2,
                                         XC1, 512, 256);

  // ---- SAGE 1: agg1 -> XC1 cols[0,256); Y = XC1 @ WC1^T (+col stats) ----
  aggregate8<<<NN / 8, 256, 0, stream>>>(XC1, 64, 32, 0, 5, XC1,
                                         offsets, srcs, inv_deg);
  mfma_gemm<<<1024, 256, 0, stream>>>(XC1, 512, wc1, 512, 512,
                                      bl1, Y, 512, GH_, 2, 1,
                                      pn1s, pn1q, nullptr, nullptr);
  pn_finalize<<<1, 512, 0, stream>>>(pn1s, pn1q, mu, invd);
  pn_apply_v<<<NN / 2, 256, 0, stream>>>(Y, mu, invd, XC2, 256, 128);  // x1 -> XC2 cols[512,1024)

  // ---- SAGE 2: agg2 -> XC2 cols[0,512); Y = XC2 @ WC2^T (+col stats) ----
  aggregate8<<<NN / 4, 256, 0, stream>>>(XC2, 128, 64, 0, 6, XC2,
                                         offsets, srcs, inv_deg);
  mfma_gemm<<<1024, 256, 0, stream>>>(XC2, 1024, wc2, 1024, 1024,
                                      bl2, Y, 512, GH_, 2, 1,
                                      pn2s, pn2q, nullptr, nullptr);
  pn_finalize<<<1, 512, 0, stream>>>(pn2s, pn2q, mu, invd);
  pn_apply_v<<<NN / 2, 256, 0, stream>>>(Y, mu, invd, XC2, 256, 128);  // x2 overwrites x1

  // ---- SAGE 3 + head: agg3 -> XC2 cols[0,512); out[seg] += pooled head ----
  aggregate8<<<NN / 4, 256, 0, stream>>>(XC2, 128, 64, 0, 6, XC2,
                                         offsets, srcs, inv_deg);
  mfma_gemm<<<1024, 256, 0, stream>>>(XC2, 1024, wc3, 1024, 1024,
                                      bl3, nullptr, 512, GH_, 3, 1,
                                      nullptr, nullptr, wc, out);
}